// Round 8
// baseline (2219.699 us; speedup 1.0000x reference)
//
#include <hip/hip_runtime.h>
#include <hip/hip_bf16.h>

#define B_SZ  64
#define S_LEN 512
#define I_DIM 1024
#define H_DIM 1024
#define BHE   (B_SZ * H_DIM)          // 65536 elems per h buffer

typedef __bf16 bf16x8 __attribute__((ext_vector_type(8)));
typedef __bf16 bf16x4 __attribute__((ext_vector_type(4)));
typedef float  f32x4  __attribute__((ext_vector_type(4)));
typedef unsigned u32x4 __attribute__((ext_vector_type(4)));

#define MFMA16(a,b,c) __builtin_amdgcn_mfma_f32_16x16x32_bf16((a),(b),(c),0,0,0)

__device__ inline bf16x8 cvt8(const float4& a, const float4& b) {
  bf16x8 v;
  v[0]=(__bf16)a.x; v[1]=(__bf16)a.y; v[2]=(__bf16)a.z; v[3]=(__bf16)a.w;
  v[4]=(__bf16)b.x; v[5]=(__bf16)b.y; v[6]=(__bf16)b.z; v[7]=(__bf16)b.w;
  return v;
}
__device__ inline bf16x8 asb(u32x4 v) { return __builtin_bit_cast(bf16x8, v); }
__device__ inline unsigned long long pack4(const f32x4& r) {
  bf16x4 h;
  h[0]=(__bf16)r[0]; h[1]=(__bf16)r[1]; h[2]=(__bf16)r[2]; h[3]=(__bf16)r[3];
  return __builtin_bit_cast(unsigned long long, h);
}

// ---- asm memory helpers ----
template<int OFF>
__device__ __forceinline__ u32x4 ldsc(const void* p) {   // LLC-coherent, +imm
  u32x4 r;
  asm volatile("global_load_dwordx4 %0, %1, off offset:%2 sc0 sc1"
               : "=v"(r) : "v"(p), "i"(OFF));
  return r;
}
__device__ __forceinline__ void st64_sc(void* p, unsigned long long v) {
  asm volatile("global_store_dwordx2 %0, %1, off sc0 sc1"
               :: "v"(p), "v"(v) : "memory");
}
#define VMW(N) do { asm volatile("s_waitcnt vmcnt(%0)" :: "i"(N)); \
                    __builtin_amdgcn_sched_barrier(0); } while (0)
#define VMWF(N) do { asm volatile("s_waitcnt vmcnt(%0)" :: "i"(N) : "memory"); \
                     __builtin_amdgcn_sched_barrier(0); } while (0)

// ---- phase 0: h0 fp32 -> ht[0] bf16 (sc) ----
__global__ void k_hinit(const float* __restrict__ h0, __bf16* __restrict__ ht) {
  const int ci = blockIdx.x * 256 + threadIdx.x;   // 16384 f32x4 quads
  const float4 v = ((const float4*)h0)[ci];
  bf16x4 hv;
  hv[0] = (__bf16)v.x; hv[1] = (__bf16)v.y; hv[2] = (__bf16)v.z; hv[3] = (__bf16)v.w;
  st64_sc(ht + (size_t)ci * 4, __builtin_bit_cast(unsigned long long, hv));
}

// ---- phase 1: x_proj = seq @ w_ih^T + b_ih -> d_out (unchanged, proven) ----
#define P1_LDA 40
__global__ __launch_bounds__(256, 2) void k_xproj(
    const float* __restrict__ A, const float* __restrict__ W,
    const float* __restrict__ bias, float* __restrict__ C) {
  constexpr int K = I_DIM, N = H_DIM;
  __shared__ __bf16 As[128][P1_LDA];
  __shared__ __bf16 Bs[128][P1_LDA];
  const int bid = blockIdx.x;
  const int nt = bid & 7, mt = bid >> 3;
  const int m0 = mt * 128, n0 = nt * 128;
  const int tid = threadIdx.x, lane = tid & 63, wv = tid >> 6;
  const int wm = (wv & 1) * 64, wn = (wv >> 1) * 64;
  const int fr = lane & 15, fq = lane >> 4;
  const int srow = tid >> 1, scol = (tid & 1) * 16;
  const float* gA = A + (size_t)(m0 + srow) * K + scol;
  const float* gB = W + (size_t)(n0 + srow) * K + scol;
  const f32x4 zero = {0.f, 0.f, 0.f, 0.f};
  f32x4 acc[4][4];
  #pragma unroll
  for (int m = 0; m < 4; ++m)
    #pragma unroll
    for (int n = 0; n < 4; ++n) acc[m][n] = zero;

  for (int k0 = 0; k0 < K; k0 += 32) {
    float4 a0 = *(const float4*)(gA + k0);
    float4 a1 = *(const float4*)(gA + k0 + 4);
    float4 a2 = *(const float4*)(gA + k0 + 8);
    float4 a3 = *(const float4*)(gA + k0 + 12);
    float4 b0 = *(const float4*)(gB + k0);
    float4 b1 = *(const float4*)(gB + k0 + 4);
    float4 b2 = *(const float4*)(gB + k0 + 8);
    float4 b3 = *(const float4*)(gB + k0 + 12);
    __syncthreads();
    *(bf16x8*)(&As[srow][scol])     = cvt8(a0, a1);
    *(bf16x8*)(&As[srow][scol + 8]) = cvt8(a2, a3);
    *(bf16x8*)(&Bs[srow][scol])     = cvt8(b0, b1);
    *(bf16x8*)(&Bs[srow][scol + 8]) = cvt8(b2, b3);
    __syncthreads();
    bf16x8 af[4], bfr[4];
    #pragma unroll
    for (int m = 0; m < 4; ++m) af[m]  = *(const bf16x8*)(&As[wm + m*16 + fr][fq*8]);
    #pragma unroll
    for (int n = 0; n < 4; ++n) bfr[n] = *(const bf16x8*)(&Bs[wn + n*16 + fr][fq*8]);
    #pragma unroll
    for (int m = 0; m < 4; ++m)
      #pragma unroll
      for (int n = 0; n < 4; ++n)
        acc[m][n] = MFMA16(af[m], bfr[n], acc[m][n]);
  }
  #pragma unroll
  for (int n = 0; n < 4; ++n) {
    const int col = n0 + wn + n*16 + fr;
    const float bv = bias[col];
    #pragma unroll
    for (int m = 0; m < 4; ++m) {
      const int row = m0 + wm + m*16 + fq*4;
      #pragma unroll
      for (int jj = 0; jj < 4; ++jj)
        C[(size_t)(row + jj) * N + col] = acc[m][n][jj] + bv;
    }
  }
}

// ---- phase 2: persistent recurrence, 1 wave/CU, B direct from LLC ----
// Identical to round 7 except the poll waits vmcnt(0): vmcnt retires IN
// ISSUE ORDER, so with 4 older x-prefetch loads outstanding, vmcnt(4) did
// NOT cover the flag load -> garbage flag -> spurious poll exit (round-7
// correctness failure). vmcnt(0) makes the flag value architectural; the
// x-prefetches it also drains were issued a full phase earlier (done).
#define NGRP 2

#define BLOADS(PFX, P)                                   \
  PFX##0 = ldsc<((4*(P)+0)*64)>(hbT0);                   \
  PFX##1 = ldsc<((4*(P)+0)*64)>(hbT1);                   \
  PFX##2 = ldsc<((4*(P)+1)*64)>(hbT0);                   \
  PFX##3 = ldsc<((4*(P)+1)*64)>(hbT1);                   \
  PFX##4 = ldsc<((4*(P)+2)*64)>(hbT0);                   \
  PFX##5 = ldsc<((4*(P)+2)*64)>(hbT1);                   \
  PFX##6 = ldsc<((4*(P)+3)*64)>(hbT0);                   \
  PFX##7 = ldsc<((4*(P)+3)*64)>(hbT1);

#define KSTEP(KK, BT0, BT1)                                                  \
  { bf16x8 A0 = *(const bf16x8*)(Ws + fr1024a + ((((KK)*32) + fq8) ^ swz));  \
    bf16x8 A1 = *(const bf16x8*)(Ws + fr1024b + ((((KK)*32) + fq8) ^ swz));  \
    a00 = MFMA16(A0, asb(BT0), a00);                                         \
    a01 = MFMA16(A0, asb(BT1), a01);                                         \
    a10 = MFMA16(A1, asb(BT0), a10);                                         \
    a11 = MFMA16(A1, asb(BT1), a11); }

#define PH(PFX, P)                                       \
  KSTEP(4*(P)+0, PFX##0, PFX##1)                         \
  KSTEP(4*(P)+1, PFX##2, PFX##3)                         \
  KSTEP(4*(P)+2, PFX##4, PFX##5)                         \
  KSTEP(4*(P)+3, PFX##6, PFX##7)

__global__ __launch_bounds__(64, 1) void k_rnn(
    const float* __restrict__ w_hh, const float* __restrict__ b_hh,
    float* __restrict__ out, __bf16* __restrict__ ht,
    unsigned* __restrict__ ctrs)
{
  __shared__ __bf16 Ws[32 * 1024];                 // 64 KB
  const int bid = blockIdx.x;
  const int g = bid >> 5, j = bid & 31;
  const int r0 = j * 32, b0g = g * 32;
  const int lane = threadIdx.x & 63;
  const int fr = lane & 15, fq = lane >> 4;
  const int fq8 = fq * 8;
  const int swz = (fr << 3) ^ ((fr & 3) << 7);     // injective 64-slot swizzle
  const int fr1024a = fr * 1024, fr1024b = (16 + fr) * 1024;

  // ---- stage W once: 32 rows x 1024 fp32 -> bf16, swizzled ----
  for (int c = lane; c < 4096; c += 64) {
    const int r = c >> 7, k = (c & 127) << 3;
    const float* src = w_hh + (size_t)(r0 + r) * H_DIM + k;
    float4 w0 = *(const float4*)src;
    float4 w1 = *(const float4*)(src + 4);
    const int sz = ((r & 15) << 3) ^ ((r & 3) << 7);
    *(bf16x8*)(Ws + r * 1024 + (k ^ sz)) = cvt8(w0, w1);
  }
  asm volatile("s_waitcnt lgkmcnt(0)");            // LDS writes visible (1 wave)
  __builtin_amdgcn_sched_barrier(0);

  const f32x4 bh0 = *(const f32x4*)(b_hh + r0 + fq * 4);
  const f32x4 bh1 = *(const f32x4*)(b_hh + r0 + 16 + fq * 4);

  const __bf16* hpar0 = ht + (size_t)(b0g + fr) * H_DIM + fq8;  // parity-0 base
  const __bf16* hpar1 = hpar0 + BHE;
  unsigned* ctrw = ctrs + (g << 6);
  const unsigned* ctrr = ctrw;
  const size_t bsh = (size_t)B_SZ * S_LEN * H_DIM;

  // x pointers: tj0/tj1 quadrant bases (ti1 = +16 floats = offset:64)
  float* xp0 = out + (size_t)(b0g + fr) * S_LEN * H_DIM + (r0 + fq * 4);
  float* xp1 = out + (size_t)(b0g + 16 + fr) * S_LEN * H_DIM + (r0 + fq * 4);
  f32x4 xvA, xvB, xvC, xvD;
  asm volatile("global_load_dwordx4 %0, %1, off"           : "=v"(xvA) : "v"(xp0));
  asm volatile("global_load_dwordx4 %0, %1, off offset:64" : "=v"(xvB) : "v"(xp0));
  asm volatile("global_load_dwordx4 %0, %1, off"           : "=v"(xvC) : "v"(xp1));
  asm volatile("global_load_dwordx4 %0, %1, off offset:64" : "=v"(xvD) : "v"(xp1));

  for (int t = 0; t < S_LEN; ++t) {
    // ---- poll: peers' h_t at LLC (vmcnt(0): flag value architectural) ----
    {
      const unsigned tgt = (unsigned)t << 5;
      for (;;) {
        unsigned f;
        asm volatile("global_load_dword %0, %1, off sc0 sc1"
                     : "=v"(f) : "v"(ctrr));
        asm volatile("s_waitcnt vmcnt(0)");        // FIX: was vmcnt(4)
        __builtin_amdgcn_sched_barrier(0);
        if (f >= tgt) break;
      }
    }
    VMWF(0);                                       // (no-op; keeps fence semantics)

    const __bf16* hbT0 = (t & 1) ? hpar1 : hpar0;
    const __bf16* hbT1 = hbT0 + 16 * H_DIM;

    // ---- K loop: 8 phases, 3-bank counted-vmcnt pipeline ----
    u32x4 bA0,bA1,bA2,bA3,bA4,bA5,bA6,bA7;
    u32x4 bB0,bB1,bB2,bB3,bB4,bB5,bB6,bB7;
    u32x4 bC0,bC1,bC2,bC3,bC4,bC5,bC6,bC7;
    const f32x4 z = {0.f, 0.f, 0.f, 0.f};
    f32x4 a00 = z, a01 = z, a10 = z, a11 = z;
    BLOADS(bA, 0) BLOADS(bB, 1) BLOADS(bC, 2)
    VMW(16); PH(bA, 0) BLOADS(bA, 3)
    VMW(16); PH(bB, 1) BLOADS(bB, 4)
    VMW(16); PH(bC, 2) BLOADS(bC, 5)
    VMW(16); PH(bA, 3) BLOADS(bA, 6)
    VMW(16); PH(bB, 4) BLOADS(bB, 7)
    VMW(16); PH(bC, 5)
    VMW(8);  PH(bA, 6)
    VMW(0);  PH(bB, 7)

    // ---- epilogue: r = relu(x + hW^T + b) ----
    f32x4 rA, rB, rC, rD;
    #pragma unroll
    for (int i = 0; i < 4; ++i) {
      rA[i] = fmaxf(xvA[i] + a00[i] + bh0[i], 0.f);
      rB[i] = fmaxf(xvB[i] + a10[i] + bh1[i], 0.f);
      rC[i] = fmaxf(xvC[i] + a01[i] + bh0[i], 0.f);
      rD[i] = fmaxf(xvD[i] + a11[i] + bh1[i], 0.f);
    }
    *(f32x4*)xp0 = rA; *(f32x4*)(xp0 + 16) = rB;   // overwrite x_t with h_t
    *(f32x4*)xp1 = rC; *(f32x4*)(xp1 + 16) = rD;
    __bf16* hw = ht + (((t + 1) & 1) ? BHE : 0);
    __bf16* hwA = hw + ((size_t)(b0g + fr) << 10) + r0 + fq * 4;
    __bf16* hwC = hwA + (16 << 10);
    st64_sc(hwA,      pack4(rA));
    st64_sc(hwA + 16, pack4(rB));
    st64_sc(hwC,      pack4(rC));
    st64_sc(hwC + 16, pack4(rD));
    if (t == S_LEN - 1) {
      float* hl = out + bsh;
      *(f32x4*)(hl + ((size_t)(b0g + fr) << 10) + r0 + fq * 4)      = rA;
      *(f32x4*)(hl + ((size_t)(b0g + fr) << 10) + r0 + fq * 4 + 16) = rB;
      *(f32x4*)(hl + ((size_t)(b0g + 16 + fr) << 10) + r0 + fq * 4)      = rC;
      *(f32x4*)(hl + ((size_t)(b0g + 16 + fr) << 10) + r0 + fq * 4 + 16) = rD;
    }
    VMWF(0);                                       // h + out drained to LLC
    if (lane == 0)
      __hip_atomic_fetch_add(ctrw, 1u, __ATOMIC_RELAXED, __HIP_MEMORY_SCOPE_AGENT);
    // x_{t+1} prefetch (after arrive: off the critical path)
    xp0 += H_DIM; xp1 += H_DIM;
    asm volatile("global_load_dwordx4 %0, %1, off"           : "=v"(xvA) : "v"(xp0));
    asm volatile("global_load_dwordx4 %0, %1, off offset:64" : "=v"(xvB) : "v"(xp0));
    asm volatile("global_load_dwordx4 %0, %1, off"           : "=v"(xvC) : "v"(xp1));
    asm volatile("global_load_dwordx4 %0, %1, off offset:64" : "=v"(xvD) : "v"(xp1));
  }
}

extern "C" void kernel_launch(void* const* d_in, const int* in_sizes, int n_in,
                              void* d_out, int out_size, void* d_ws, size_t ws_size,
                              hipStream_t stream) {
  const float* seq  = (const float*)d_in[0];
  const float* h0   = (const float*)d_in[1];
  const float* w_ih = (const float*)d_in[2];
  const float* w_hh = (const float*)d_in[3];
  const float* b_ih = (const float*)d_in[4];
  const float* b_hh = (const float*)d_in[5];
  float* out = (float*)d_out;

  __bf16* ht = (__bf16*)d_ws;                               // [2][B][H] bf16
  unsigned* ctrs = (unsigned*)((char*)d_ws + (size_t)2 * BHE * sizeof(__bf16));

  hipMemsetAsync(ctrs, 0, NGRP * 64 * sizeof(unsigned), stream);
  k_hinit<<<dim3(BHE / 4 / 256), dim3(256), 0, stream>>>(h0, ht);
  k_xproj<<<dim3((B_SZ * S_LEN / 128) * (H_DIM / 128)), dim3(256), 0, stream>>>(
      seq, w_ih, b_ih, out);

  const float* a0 = w_hh; const float* a1 = b_hh; float* a2 = out;
  __bf16* a3 = ht; unsigned* a4 = ctrs;
  void* args[5] = { &a0, &a1, &a2, &a3, &a4 };
  hipLaunchCooperativeKernel((void*)k_rnn, dim3(NGRP * 32), dim3(64),
                             args, 0, stream);
}

// Round 10
// 2109.706 us; speedup vs baseline: 1.0521x; 1.0521x over previous
//
#include <hip/hip_runtime.h>
#include <hip/hip_bf16.h>

#define B_SZ  64
#define S_LEN 512
#define I_DIM 1024
#define H_DIM 1024
#define BHE   (B_SZ * H_DIM)          // 65536 elems per h buffer

typedef __bf16 bf16x8 __attribute__((ext_vector_type(8)));
typedef __bf16 bf16x4 __attribute__((ext_vector_type(4)));
typedef float  f32x4  __attribute__((ext_vector_type(4)));
typedef unsigned u32x4 __attribute__((ext_vector_type(4)));

#define MFMA16(a,b,c) __builtin_amdgcn_mfma_f32_16x16x32_bf16((a),(b),(c),0,0,0)

__device__ inline bf16x8 cvt8(const float4& a, const float4& b) {
  bf16x8 v;
  v[0]=(__bf16)a.x; v[1]=(__bf16)a.y; v[2]=(__bf16)a.z; v[3]=(__bf16)a.w;
  v[4]=(__bf16)b.x; v[5]=(__bf16)b.y; v[6]=(__bf16)b.z; v[7]=(__bf16)b.w;
  return v;
}
__device__ inline bf16x8 cvt8v(const f32x4& a, const f32x4& b) {
  bf16x8 v;
  v[0]=(__bf16)a[0]; v[1]=(__bf16)a[1]; v[2]=(__bf16)a[2]; v[3]=(__bf16)a[3];
  v[4]=(__bf16)b[0]; v[5]=(__bf16)b[1]; v[6]=(__bf16)b[2]; v[7]=(__bf16)b[3];
  return v;
}
__device__ inline unsigned long long pack4(const f32x4& r) {
  bf16x4 h;
  h[0]=(__bf16)r[0]; h[1]=(__bf16)r[1]; h[2]=(__bf16)r[2]; h[3]=(__bf16)r[3];
  return __builtin_bit_cast(unsigned long long, h);
}

// ---- LLC-coherent (bypass L1/L2) helpers — the PROVEN cross-XCD path ----
__device__ inline u32x4 load_b128_sc(const void* p) {
  u32x4 r;
  asm volatile("global_load_dwordx4 %0, %1, off sc0 sc1"
               : "=v"(r) : "v"(p) : "memory");
  return r;
}
__device__ inline void st64_sc(void* p, unsigned long long v) {
  asm volatile("global_store_dwordx2 %0, %1, off sc0 sc1"
               :: "v"(p), "v"(v) : "memory");
}
__device__ inline f32x4 load_b128_pf(const void* p) {   // normal cached load
  f32x4 r;
  asm volatile("global_load_dwordx4 %0, %1, off" : "=v"(r) : "v"(p) : "memory");
  return r;
}
__device__ inline void waitcnt_vm0() {
  asm volatile("s_waitcnt vmcnt(0)" ::: "memory");
}

// ---- phase 0: h0 fp32 -> ht[0] bf16 (sc); zero 256 flags (replay-safe) ----
__global__ void k_hinit(const float* __restrict__ h0, __bf16* __restrict__ ht,
                        unsigned* __restrict__ flags) {
  const int ci = blockIdx.x * 256 + threadIdx.x;   // 16384 f32x4 quads
  const float4 v = ((const float4*)h0)[ci];
  bf16x4 hv;
  hv[0] = (__bf16)v.x; hv[1] = (__bf16)v.y; hv[2] = (__bf16)v.z; hv[3] = (__bf16)v.w;
  st64_sc(ht + (size_t)ci * 4, __builtin_bit_cast(unsigned long long, hv));
  if (blockIdx.x == 0) {                           // 256 flag slots (4 grp x 64)
    unsigned z = 0u;
    asm volatile("global_store_dword %0, %1, off sc0 sc1"
                 :: "v"(flags + threadIdx.x), "v"(z) : "memory");
  }
}

// ---- phase 1: x_proj = seq @ w_ih^T + b_ih -> d_out (unchanged, proven) ----
#define P1_LDA 40
__global__ __launch_bounds__(256, 2) void k_xproj(
    const float* __restrict__ A, const float* __restrict__ W,
    const float* __restrict__ bias, float* __restrict__ C) {
  constexpr int K = I_DIM, N = H_DIM;
  __shared__ __bf16 As[128][P1_LDA];
  __shared__ __bf16 Bs[128][P1_LDA];
  const int bid = blockIdx.x;
  const int nt = bid & 7, mt = bid >> 3;
  const int m0 = mt * 128, n0 = nt * 128;
  const int tid = threadIdx.x, lane = tid & 63, wv = tid >> 6;
  const int wm = (wv & 1) * 64, wn = (wv >> 1) * 64;
  const int fr = lane & 15, fq = lane >> 4;
  const int srow = tid >> 1, scol = (tid & 1) * 16;
  const float* gA = A + (size_t)(m0 + srow) * K + scol;
  const float* gB = W + (size_t)(n0 + srow) * K + scol;
  const f32x4 zero = {0.f, 0.f, 0.f, 0.f};
  f32x4 acc[4][4];
  #pragma unroll
  for (int m = 0; m < 4; ++m)
    #pragma unroll
    for (int n = 0; n < 4; ++n) acc[m][n] = zero;

  for (int k0 = 0; k0 < K; k0 += 32) {
    float4 a0 = *(const float4*)(gA + k0);
    float4 a1 = *(const float4*)(gA + k0 + 4);
    float4 a2 = *(const float4*)(gA + k0 + 8);
    float4 a3 = *(const float4*)(gA + k0 + 12);
    float4 b0 = *(const float4*)(gB + k0);
    float4 b1 = *(const float4*)(gB + k0 + 4);
    float4 b2 = *(const float4*)(gB + k0 + 8);
    float4 b3 = *(const float4*)(gB + k0 + 12);
    __syncthreads();
    *(bf16x8*)(&As[srow][scol])     = cvt8(a0, a1);
    *(bf16x8*)(&As[srow][scol + 8]) = cvt8(a2, a3);
    *(bf16x8*)(&Bs[srow][scol])     = cvt8(b0, b1);
    *(bf16x8*)(&Bs[srow][scol + 8]) = cvt8(b2, b3);
    __syncthreads();
    bf16x8 af[4], bfr[4];
    #pragma unroll
    for (int m = 0; m < 4; ++m) af[m]  = *(const bf16x8*)(&As[wm + m*16 + fr][fq*8]);
    #pragma unroll
    for (int n = 0; n < 4; ++n) bfr[n] = *(const bf16x8*)(&Bs[wn + n*16 + fr][fq*8]);
    #pragma unroll
    for (int m = 0; m < 4; ++m)
      #pragma unroll
      for (int n = 0; n < 4; ++n)
        acc[m][n] = MFMA16(af[m], bfr[n], acc[m][n]);
  }
  #pragma unroll
  for (int n = 0; n < 4; ++n) {
    const int col = n0 + wn + n*16 + fr;
    const float bv = bias[col];
    #pragma unroll
    for (int m = 0; m < 4; ++m) {
      const int row = m0 + wm + m*16 + fq*4;
      #pragma unroll
      for (int jj = 0; jj < 4; ++jj)
        C[(size_t)(row + jj) * N + col] = acc[m][n][jj] + bv;
    }
  }
}

// ---- phase 2: persistent recurrence (round-2 body, lean wave-flag sync) ----
// 4 groups x 16 batches; 16 WGs/group x 256 thr (4 waves); WG owns 64 rows,
// wave owns 16. h ping-pongs at the LLC (sc0 sc1, proven). Sync redesign:
//  * producer: each WAVE stores its h slice, vmcnt(0)-drains, lane0 writes
//    flag[j*4+wv]=t+1 (single writer, monotone). NO WG sync, NO atomic.
//  * consumer: thread tid's staged chunks all have k=(tid&127)*8, i.e. ONE
//    producer wave (flag p=(tid&127)>>1). Wave polls its 32 needed flags
//    (__all), issues stage loads immediately; stage __syncthreads joins WG.
// Lifetime (re-derived): flag_W >= t certifies W finished reading parity
// (t-1)&1 = (t+1)&1, so writing h_{t+1} there is safe once all flags >= t
// were observed at the stage barrier this step.
#define NGR 4
#define BG  16
#define WPG 16
#define RPW 64

__global__ __launch_bounds__(256, 1) void k_rnn(
    const float* __restrict__ w_hh, const float* __restrict__ b_hh,
    float* __restrict__ out, __bf16* __restrict__ ht,
    unsigned* __restrict__ flags)
{
  __shared__ __bf16 Hs[BG][H_DIM];               // 32 KB, XOR-swizzled
  const int bid = blockIdx.x;
  const int g = bid >> 4, j = bid & 15;
  const int r0 = j * RPW;
  const int tid = threadIdx.x, lane = tid & 63, wv = tid >> 6;
  const int fr = lane & 15, fq = lane >> 4;
  const int myW  = r0 + wv * 16 + fr;            // A-frag W row
  const int row4 = r0 + wv * 16 + fq * 4;        // 4 consecutive output rows
  const int b    = g * BG + fr;                  // batch (D col)
  const int hswz = (fr & 7) << 3;

  // W fragments (round-2 proven; live in AGPR/VGPR unified file)
  bf16x8 wfrag[32];
  {
    const float* wsrc = w_hh + (size_t)myW * H_DIM + fq * 8;
    #pragma unroll
    for (int kk = 0; kk < 32; ++kk) {
      f32x4 w0 = *(const f32x4*)(wsrc + kk * 32);
      f32x4 w1 = *(const f32x4*)(wsrc + kk * 32 + 4);
      wfrag[kk] = cvt8v(w0, w1);
    }
  }
  const f32x4 bh = *(const f32x4*)(b_hh + row4);
  const size_t bsh = (size_t)B_SZ * S_LEN * H_DIM;
  const __bf16* hg0 = ht + (size_t)g * BG * H_DIM;      // group block, buf0
  unsigned* fgrp = flags + (g << 6);                    // 64 flags (1/wave)
  const unsigned* fpoll = fgrp + ((tid & 127) >> 1);    // my producer wave
  unsigned* myfp = fgrp + (j << 2) + wv;                // my flag slot

  size_t xo = (size_t)b * S_LEN * H_DIM + row4;
  f32x4 xv = load_b128_pf(out + xo);             // t=0 x prefetch

  for (int t = 0; t < S_LEN; ++t) {
    // ---- poll: only the 32 producer waves this wave's threads consume ----
    if (t) {
      const unsigned tt = (unsigned)t;
      for (;;) {
        unsigned f;
        asm volatile("global_load_dword %0, %1, off sc0 sc1"
                     : "=v"(f) : "v"(fpoll) : "memory");
        waitcnt_vm0();
        __builtin_amdgcn_sched_barrier(0);
        if (__all((int)(f >= tt))) break;
      }
    }

    // ---- stage h_t: LLC -> LDS (2048 x 16B, round-2 proven layout) ----
    const __bf16* hsrc = hg0 + (size_t)(t & 1) * BHE;
    u32x4 st[8];
    #pragma unroll
    for (int i = 0; i < 8; ++i)
      st[i] = load_b128_sc(hsrc + (size_t)(tid + (i << 8)) * 8);
    waitcnt_vm0();
    __builtin_amdgcn_sched_barrier(0);
    #pragma unroll
    for (int i = 0; i < 8; ++i) {
      const int c = tid + (i << 8);
      const int bb = c >> 7, k = (c & 127) << 3;
      *(u32x4*)&Hs[bb][k ^ ((bb & 7) << 3)] = st[i];
    }
    __syncthreads();                             // stage complete (WG join)

    // ---- MFMA: 32 x 16x16x32, 4 acc chains (round-2 proven) ----
    const f32x4 z = {0.f, 0.f, 0.f, 0.f};
    f32x4 a0 = z, a1 = z, a2 = z, a3 = z;
    #pragma unroll
    for (int kk = 0; kk < 32; kk += 4) {
      bf16x8 h0 = *(const bf16x8*)&Hs[fr][((kk + 0) * 32 + fq * 8) ^ hswz];
      a0 = MFMA16(wfrag[kk + 0], h0, a0);
      bf16x8 h1 = *(const bf16x8*)&Hs[fr][((kk + 1) * 32 + fq * 8) ^ hswz];
      a1 = MFMA16(wfrag[kk + 1], h1, a1);
      bf16x8 h2 = *(const bf16x8*)&Hs[fr][((kk + 2) * 32 + fq * 8) ^ hswz];
      a2 = MFMA16(wfrag[kk + 2], h2, a2);
      bf16x8 h3 = *(const bf16x8*)&Hs[fr][((kk + 3) * 32 + fq * 8) ^ hswz];
      a3 = MFMA16(wfrag[kk + 3], h3, a3);
    }
    __syncthreads();                             // Hs reuse guard (all reads done)

    // ---- epilogue: r = relu(x + hW^T + b); h store, drain, PER-WAVE flag ----
    f32x4 s = (a0 + a1) + (a2 + a3);
    f32x4 r;
    r[0] = fmaxf(xv[0] + s[0] + bh[0], 0.f);
    r[1] = fmaxf(xv[1] + s[1] + bh[1], 0.f);
    r[2] = fmaxf(xv[2] + s[2] + bh[2], 0.f);
    r[3] = fmaxf(xv[3] + s[3] + bh[3], 0.f);
    __bf16* hd = ht + (size_t)((t + 1) & 1) * BHE + (size_t)b * H_DIM + row4;
    st64_sc(hd, pack4(r));
    waitcnt_vm0();                               // this wave's h at LLC
    if (lane == 0) {
      const unsigned tv = (unsigned)(t + 1);
      asm volatile("global_store_dword %0, %1, off sc0 sc1"
                   :: "v"(myfp), "v"(tv) : "memory");
    }
    // off the critical path: out (cached), h_last, x prefetch
    *(f32x4*)(out + xo) = r;                     // overwrite x_t with h_t
    if (t == S_LEN - 1)
      *(f32x4*)(out + bsh + (size_t)b * H_DIM + row4) = r;
    xo += H_DIM;
    xv = load_b128_pf(out + xo);                 // x_{t+1} prefetch
  }
}

extern "C" void kernel_launch(void* const* d_in, const int* in_sizes, int n_in,
                              void* d_out, int out_size, void* d_ws, size_t ws_size,
                              hipStream_t stream) {
  const float* seq  = (const float*)d_in[0];
  const float* h0   = (const float*)d_in[1];
  const float* w_ih = (const float*)d_in[2];
  const float* w_hh = (const float*)d_in[3];
  const float* b_ih = (const float*)d_in[4];
  const float* b_hh = (const float*)d_in[5];
  float* out = (float*)d_out;

  __bf16* ht = (__bf16*)d_ws;                               // [2][B][H] bf16
  unsigned* flags = (unsigned*)((char*)d_ws + (size_t)2 * BHE * sizeof(__bf16));

  k_hinit<<<dim3(BHE / 4 / 256), dim3(256), 0, stream>>>(h0, ht, flags);
  k_xproj<<<dim3((B_SZ * S_LEN / 128) * (H_DIM / 128)), dim3(256), 0, stream>>>(
      seq, w_ih, b_ih, out);

  const float* a0 = w_hh; const float* a1 = b_hh; float* a2 = out;
  __bf16* a3 = ht; unsigned* a4 = flags;
  void* args[5] = { &a0, &a1, &a2, &a3, &a4 };
  hipLaunchCooperativeKernel((void*)k_rnn, dim3(NGR * WPG), dim3(256),
                             args, 0, stream);
}